// Round 18
// baseline (172.487 us; speedup 1.0000x reference)
//
#include <hip/hip_runtime.h>
#include <hip/hip_bf16.h>
#include <math.h>

#define BB 32
#define SS 1024
#define DH 512      // DEC_HID
#define EH2 1024    // 2*ENC_HID
#define WROW 1536   // in_dim
#define NEGV -1.0e10f

typedef __attribute__((ext_vector_type(8))) short s16x8;
typedef __attribute__((ext_vector_type(4))) float f32x4;
typedef unsigned short u16;
typedef unsigned int u32;

// B LDS row = 128 B: [hi k0..31 | lo k0..31], 8 slots of 16 B, XOR-swizzled.
__device__ __forceinline__ int swzB(int row, int slot) {
    return row * 64 + ((slot ^ (row & 7)) << 3);
}
// A LDS row = 64 B (hi only): 4 slots of 16 B; 2-way-free swizzle.
__device__ __forceinline__ int swzA(int row, int slot) {
    return row * 32 + ((slot ^ ((row >> 1) & 3)) << 3);
}

__device__ __forceinline__ void split8(const float4& v0, const float4& v1,
                                       s16x8& hi, s16x8& lo) {
    float xs[8] = {v0.x, v0.y, v0.z, v0.w, v1.x, v1.y, v1.z, v1.w};
    union { u16 u[8]; s16x8 v; } H, L;
#pragma unroll
    for (int j = 0; j < 8; ++j) {
        u32 u = __builtin_bit_cast(u32, xs[j]);
        u32 hb = u & 0xFFFF0000u;
        float rem = xs[j] - __builtin_bit_cast(float, hb);
        H.u[j] = (u16)(u >> 16);
        L.u[j] = __builtin_bit_cast(u16, __float2bfloat16(rem));
    }
    hi = H.v;
    lo = L.v;
}

__device__ __forceinline__ s16x8 cvt8(const float4& v0, const float4& v1) {
    float xs[8] = {v0.x, v0.y, v0.z, v0.w, v1.x, v1.y, v1.z, v1.w};
    union { u16 u[8]; s16x8 v; } H;
#pragma unroll
    for (int j = 0; j < 8; ++j)
        H.u[j] = __builtin_bit_cast(u16, __float2bfloat16(xs[j]));   // RNE
    return H.v;
}

__device__ __forceinline__ float fast_tanh(float x) {
    float a = fabsf(x);
    float e = __expf(2.0f * a);
    float r = 1.0f - 2.0f / (e + 1.0f);   // e->inf gives r=1, no NaN
    return copysignf(r, x);
}

// ---------------- Prep kernel: fused bsplit (blocks 0..255) + hproj (256..4351)
__global__ void prep_kernel(const float* __restrict__ W,
                            const float* __restrict__ hidden,
                            const float* __restrict__ bias,
                            u16* __restrict__ img,
                            float* __restrict__ hproj) {
    if (blockIdx.x < 256) {
        int idx = blockIdx.x * 256 + threadIdx.x;   // 512 cols * 128 k-octets
        int c = idx >> 7;         // 0..511 (We row = output col d)
        int ko = idx & 127;       // k-octet 0..127
        int k = ko * 8;
        const float* src = W + (size_t)c * WROW + DH + k;
        float4 v0 = *(const float4*)src;
        float4 v1 = *(const float4*)(src + 4);
        s16x8 hi, lo;
        split8(v0, v1, hi, lo);
        int nb = c >> 8;          // n-block (256 cols each)
        int cp = c & 255;         // col within tile
        int kt = ko >> 2;         // K-step
        int sl = ko & 3;          // hi slot
        u16* tb = img + ((size_t)(nb * 32 + kt) << 14);   // 16384 u16 per tile
        *(s16x8*)(tb + swzB(cp, sl)) = hi;
        *(s16x8*)(tb + swzB(cp, sl + 4)) = lo;
    } else {
        int wave = (int)(((blockIdx.x - 256) * blockDim.x + threadIdx.x) >> 6);
        int lane = threadIdx.x & 63;
        if (wave >= BB * DH) return;
        int b = wave >> 9;
        int d = wave & 511;
        const float* hrow = hidden + b * DH;
        const float* wrow = W + (size_t)d * WROW;
        float sum = 0.f;
#pragma unroll
        for (int u = 0; u < 8; ++u) {
            int k = lane + 64 * u;
            sum = fmaf(hrow[k], wrow[k], sum);
        }
#pragma unroll
        for (int off = 32; off > 0; off >>= 1)
            sum += __shfl_xor(sum, off, 64);
        if (lane == 0) hproj[wave] = sum + bias[d];
    }
}

// ---------------- Kernel B: 128s x 256d block, 8 waves (2x4), wave-tile 64x64,
// 2-product bf16 split (A hi-only), FULL double-buffer, ONE barrier per K-step.
// Fused masked-softmax tail: last of the 16 blocks of a batch-row does softmax.
// LDS 80 KB -> 2 blocks/CU. grid: 512 blocks (256 m x 2 nb, XCD-chunked).
__global__ __launch_bounds__(512, 4)
void energy_mfma_kernel(const float* __restrict__ enc,
                        const u16* __restrict__ bimg,
                        const float* __restrict__ hproj,
                        const float* __restrict__ v,
                        const int* __restrict__ mask,
                        float* __restrict__ scoresP,
                        int* __restrict__ cnt,
                        float* __restrict__ out) {
    __shared__ u16 sA[2][128 * 32];     // 8 KB each (hi only)
    __shared__ u16 sB[2][256 * 64];     // 32 KB each
    __shared__ int sFlag;

    const int tid = threadIdx.x;
    const int lane = tid & 63;
    const int wid = tid >> 6;         // 0..7
    const int lr = lane & 15;
    const int lg = lane >> 4;         // 0..3

    // XCD-chunked decode (bijective: 512 = 8*64)
    const int flat = (blockIdx.x & 7) * 64 + (blockIdx.x >> 3);
    const int nblk = flat & 1;
    const int mblk = flat >> 1;       // 0..255
    const int b = mblk >> 3;
    const int srow = (mblk & 7) * 128;
    const int d0 = nblk * 256;

    const int wm = (wid >> 2) * 64;   // wave row offset (2 M-groups)
    const int wn = (wid & 3) * 64;    // wave col offset (4 N-waves)

    const float* aBase = enc + ((size_t)(b * SS + srow)) * EH2;
    const u16* tBase = bimg + (((size_t)nblk * 32) << 14);

    const int arow = tid >> 2;        // 0..127
    const int ak8 = tid & 3;          // k-octet 0..3

    f32x4 acc[4][4];
#pragma unroll
    for (int m = 0; m < 4; ++m)
#pragma unroll
        for (int n = 0; n < 4; ++n) acc[m][n] = (f32x4){0.f, 0.f, 0.f, 0.f};

    float4 rA[2];
    auto loadA = [&](int t) {
        const float* p = aBase + (size_t)arow * EH2 + t * 32 + ak8 * 8;
        rA[0] = ((const float4*)p)[0];
        rA[1] = ((const float4*)p)[1];
    };
    auto writeA = [&](int buf) {
        s16x8 hi = cvt8(rA[0], rA[1]);
        *(s16x8*)&sA[buf][swzA(arow, ak8)] = hi;
    };
    auto stageB = [&](int t, int buf) {
        const u16* tb = tBase + ((size_t)t << 14);
#pragma unroll
        for (int q = 0; q < 4; ++q) {
            int o = (wid * 4 + q) * 512;   // u16 units, 1 KB per inst
            __builtin_amdgcn_global_load_lds(
                (const __attribute__((address_space(1))) u32*)(tb + o + lane * 8),
                (__attribute__((address_space(3))) u32*)&sB[buf][o],
                16, 0, 0);
        }
    };

    auto compute = [&](int buf) {
        s16x8 bH[4], bL[4];
#pragma unroll
        for (int n = 0; n < 4; ++n) {
            int col = wn + n * 16 + lr;
            bH[n] = *(const s16x8*)&sB[buf][swzB(col, lg)];
            bL[n] = *(const s16x8*)&sB[buf][swzB(col, lg + 4)];
        }
        __builtin_amdgcn_s_setprio(1);
#pragma unroll
        for (int m = 0; m < 4; ++m) {
            int row = wm + m * 16 + lr;
            s16x8 aH = *(const s16x8*)&sA[buf][swzA(row, lg)];
#pragma unroll
            for (int n = 0; n < 4; ++n) {
                acc[m][n] = __builtin_amdgcn_mfma_f32_16x16x32_bf16(aH, bH[n], acc[m][n], 0, 0, 0);
                acc[m][n] = __builtin_amdgcn_mfma_f32_16x16x32_bf16(aH, bL[n], acc[m][n], 0, 0, 0);
            }
        }
        __builtin_amdgcn_s_setprio(0);
    };

    // ---- prologue: stage tile 0 into buf 0, prefetch A(1) regs
    loadA(0);
    stageB(0, 0);
    writeA(0);                 // auto-waits A(0); B(0) DMAs stay in flight
    loadA(1);
    asm volatile("s_waitcnt vmcnt(2) lgkmcnt(0)" ::: "memory");
    __builtin_amdgcn_s_barrier();

#pragma unroll 1
    for (int t = 0; t < 32; ++t) {
        const int cur = t & 1;
        __builtin_amdgcn_sched_barrier(0);
        if (t < 31) {
            stageB(t + 1, cur ^ 1);
            writeA(cur ^ 1);
            if (t < 30) loadA(t + 2);
        }
        compute(cur);
        if (t < 30) {
            asm volatile("s_waitcnt vmcnt(2) lgkmcnt(0)" ::: "memory");
        } else {
            asm volatile("s_waitcnt vmcnt(0) lgkmcnt(0)" ::: "memory");
        }
        __builtin_amdgcn_s_barrier();
    }

    // ---- epilogue: partial scores over this block's 256 cols, block-local
    float* sred = (float*)&sA[0][0];           // [4][128], aliased on dead sA
    float hp[4], vv[4];
#pragma unroll
    for (int n = 0; n < 4; ++n) {
        int c = d0 + wn + n * 16 + lr;
        hp[n] = hproj[b * DH + c];
        vv[n] = v[c];
    }
#pragma unroll
    for (int m = 0; m < 4; ++m)
#pragma unroll
        for (int r = 0; r < 4; ++r) {
            float p = 0.f;
#pragma unroll
            for (int n = 0; n < 4; ++n)
                p += fast_tanh(acc[m][n][r] + hp[n]) * vv[n];
            p += __shfl_xor(p, 1, 64);
            p += __shfl_xor(p, 2, 64);
            p += __shfl_xor(p, 4, 64);
            p += __shfl_xor(p, 8, 64);
            if (lr == 0)
                sred[(wid & 3) * 128 + wm + m * 16 + lg * 4 + r] = p;
        }
    __syncthreads();
    if (tid < 128) {
        float s = sred[0 * 128 + tid] + sred[1 * 128 + tid]
                + sred[2 * 128 + tid] + sred[3 * 128 + tid];
        scoresP[(size_t)nblk * BB * SS + b * SS + srow + tid] = s;
    }

    // ---- fused softmax: last of the 16 blocks for batch-row b does it
    __threadfence();                            // release scoresP writes
    if (tid == 0) sFlag = atomicAdd(&cnt[b], 1);
    __syncthreads();
    if (sFlag != 15) return;
    __threadfence();                            // acquire all 16 blocks' writes

    // 512 threads, 2 s-elements each
    float x0, x1;
    {
        int s0 = tid, s1 = tid + 512;
        float a0 = scoresP[b * SS + s0] + scoresP[BB * SS + b * SS + s0];
        float a1 = scoresP[b * SS + s1] + scoresP[BB * SS + b * SS + s1];
        if (mask[b * SS + s0] == 0) a0 = NEGV;
        if (mask[b * SS + s1] == 0) a1 = NEGV;
        x0 = a0; x1 = a1;
    }
    float* red = sred;                          // reuse LDS
    float mx = fmaxf(x0, x1);
#pragma unroll
    for (int off = 32; off > 0; off >>= 1)
        mx = fmaxf(mx, __shfl_xor(mx, off, 64));
    if (lane == 0) red[wid] = mx;
    __syncthreads();
    mx = red[0];
#pragma unroll
    for (int w = 1; w < 8; ++w) mx = fmaxf(mx, red[w]);

    x0 = expf(x0 - mx);
    x1 = expf(x1 - mx);
    float sum = x0 + x1;
#pragma unroll
    for (int off = 32; off > 0; off >>= 1)
        sum += __shfl_xor(sum, off, 64);
    __syncthreads();
    if (lane == 0) red[8 + wid] = sum;
    __syncthreads();
    sum = red[8];
#pragma unroll
    for (int w = 1; w < 8; ++w) sum += red[8 + w];
    float inv = 1.0f / sum;
    out[b * SS + tid] = x0 * inv;
    out[b * SS + tid + 512] = x1 * inv;
}

extern "C" void kernel_launch(void* const* d_in, const int* in_sizes, int n_in,
                              void* d_out, int out_size, void* d_ws, size_t ws_size,
                              hipStream_t stream) {
    const float* hidden = (const float*)d_in[0];
    const float* enc    = (const float*)d_in[1];
    const int*   mask   = (const int*)d_in[2];
    const float* W      = (const float*)d_in[3];
    const float* bias   = (const float*)d_in[4];
    const float* v      = (const float*)d_in[5];
    float* out = (float*)d_out;

    float* hproj = (float*)d_ws;                          // 64 KB
    float* scoresP = (float*)((char*)d_ws + 64 * 1024);   // 2 planes x 128 KB
    int* cnt = (int*)((char*)d_ws + 320 * 1024);          // 32 ints
    u16* bimg = (u16*)((char*)d_ws + 324 * 1024);         // 2 MB swizzled tiles

    hipMemsetAsync(cnt, 0, BB * sizeof(int), stream);

    // fused prep: blocks 0..255 = bsplit, 256..4351 = hproj
    prep_kernel<<<256 + 4096, 256, 0, stream>>>(W, hidden, bias, bimg, hproj);
    energy_mfma_kernel<<<512, 512, 0, stream>>>(enc, bimg, hproj, v, mask,
                                                scoresP, cnt, out);
}

// Round 19
// 139.813 us; speedup vs baseline: 1.2337x; 1.2337x over previous
//
#include <hip/hip_runtime.h>
#include <hip/hip_bf16.h>
#include <math.h>

#define BB 32
#define SS 1024
#define DH 512      // DEC_HID
#define EH2 1024    // 2*ENC_HID
#define WROW 1536   // in_dim
#define NEGV -1.0e10f

typedef __attribute__((ext_vector_type(8))) short s16x8;
typedef __attribute__((ext_vector_type(4))) float f32x4;
typedef unsigned short u16;
typedef unsigned int u32;

// B LDS row = 128 B: [hi k0..31 | lo k0..31], 8 slots of 16 B, XOR-swizzled.
__device__ __forceinline__ int swzB(int row, int slot) {
    return row * 64 + ((slot ^ (row & 7)) << 3);
}
// A LDS row = 64 B (hi only): 4 slots of 16 B; 2-way-free swizzle.
__device__ __forceinline__ int swzA(int row, int slot) {
    return row * 32 + ((slot ^ ((row >> 1) & 3)) << 3);
}

__device__ __forceinline__ void split8(const float4& v0, const float4& v1,
                                       s16x8& hi, s16x8& lo) {
    float xs[8] = {v0.x, v0.y, v0.z, v0.w, v1.x, v1.y, v1.z, v1.w};
    union { u16 u[8]; s16x8 v; } H, L;
#pragma unroll
    for (int j = 0; j < 8; ++j) {
        u32 u = __builtin_bit_cast(u32, xs[j]);
        u32 hb = u & 0xFFFF0000u;
        float rem = xs[j] - __builtin_bit_cast(float, hb);
        H.u[j] = (u16)(u >> 16);
        L.u[j] = __builtin_bit_cast(u16, __float2bfloat16(rem));
    }
    hi = H.v;
    lo = L.v;
}

__device__ __forceinline__ s16x8 cvt8(const float4& v0, const float4& v1) {
    float xs[8] = {v0.x, v0.y, v0.z, v0.w, v1.x, v1.y, v1.z, v1.w};
    union { u16 u[8]; s16x8 v; } H;
#pragma unroll
    for (int j = 0; j < 8; ++j)
        H.u[j] = __builtin_bit_cast(u16, __float2bfloat16(xs[j]));   // RNE
    return H.v;
}

__device__ __forceinline__ float fast_tanh(float x) {
    float a = fabsf(x);
    float e = __expf(2.0f * a);
    float r = 1.0f - 2.0f / (e + 1.0f);   // e->inf gives r=1, no NaN
    return copysignf(r, x);
}

// ---------------- Prep kernel: fused bsplit (blocks 0..255) + hproj (256..4351)
__global__ void prep_kernel(const float* __restrict__ W,
                            const float* __restrict__ hidden,
                            const float* __restrict__ bias,
                            u16* __restrict__ img,
                            float* __restrict__ hproj) {
    if (blockIdx.x < 256) {
        int idx = blockIdx.x * 256 + threadIdx.x;   // 512 cols * 128 k-octets
        int c = idx >> 7;         // 0..511 (We row = output col d)
        int ko = idx & 127;       // k-octet 0..127
        int k = ko * 8;
        const float* src = W + (size_t)c * WROW + DH + k;
        float4 v0 = *(const float4*)src;
        float4 v1 = *(const float4*)(src + 4);
        s16x8 hi, lo;
        split8(v0, v1, hi, lo);
        int nb = c >> 8;          // n-block (256 cols each)
        int cp = c & 255;         // col within tile
        int kt = ko >> 2;         // K-step
        int sl = ko & 3;          // hi slot
        u16* tb = img + ((size_t)(nb * 32 + kt) << 14);   // 16384 u16 per tile
        *(s16x8*)(tb + swzB(cp, sl)) = hi;
        *(s16x8*)(tb + swzB(cp, sl + 4)) = lo;
    } else {
        int wave = (int)(((blockIdx.x - 256) * blockDim.x + threadIdx.x) >> 6);
        int lane = threadIdx.x & 63;
        if (wave >= BB * DH) return;
        int b = wave >> 9;
        int d = wave & 511;
        const float* hrow = hidden + b * DH;
        const float* wrow = W + (size_t)d * WROW;
        float sum = 0.f;
#pragma unroll
        for (int u = 0; u < 8; ++u) {
            int k = lane + 64 * u;
            sum = fmaf(hrow[k], wrow[k], sum);
        }
#pragma unroll
        for (int off = 32; off > 0; off >>= 1)
            sum += __shfl_xor(sum, off, 64);
        if (lane == 0) hproj[wave] = sum + bias[d];
    }
}

// ---------------- Kernel B: 128s x 256d block, 8 waves (2x4), wave-tile 64x64,
// 2-product bf16 split (A hi-only), FULL double-buffer, ONE barrier per K-step.
// Fused masked-softmax tail (flag aliased into dead sA[1] -> LDS stays 80 KB).
// LDS 80 KB -> 2 blocks/CU. grid: 512 blocks (256 m x 2 nb, XCD-chunked).
__global__ __launch_bounds__(512, 4)
void energy_mfma_kernel(const float* __restrict__ enc,
                        const u16* __restrict__ bimg,
                        const float* __restrict__ hproj,
                        const float* __restrict__ v,
                        const int* __restrict__ mask,
                        float* __restrict__ scoresP,
                        int* __restrict__ cnt,
                        float* __restrict__ out) {
    __shared__ u16 sA[2][128 * 32];     // 8 KB each (hi only)
    __shared__ u16 sB[2][256 * 64];     // 32 KB each

    const int tid = threadIdx.x;
    const int lane = tid & 63;
    const int wid = tid >> 6;         // 0..7
    const int lr = lane & 15;
    const int lg = lane >> 4;         // 0..3

    // XCD-chunked decode (bijective: 512 = 8*64)
    const int flat = (blockIdx.x & 7) * 64 + (blockIdx.x >> 3);
    const int nblk = flat & 1;
    const int mblk = flat >> 1;       // 0..255
    const int b = mblk >> 3;
    const int srow = (mblk & 7) * 128;
    const int d0 = nblk * 256;

    const int wm = (wid >> 2) * 64;   // wave row offset (2 M-groups)
    const int wn = (wid & 3) * 64;    // wave col offset (4 N-waves)

    const float* aBase = enc + ((size_t)(b * SS + srow)) * EH2;
    const u16* tBase = bimg + (((size_t)nblk * 32) << 14);

    const int arow = tid >> 2;        // 0..127
    const int ak8 = tid & 3;          // k-octet 0..3

    f32x4 acc[4][4];
#pragma unroll
    for (int m = 0; m < 4; ++m)
#pragma unroll
        for (int n = 0; n < 4; ++n) acc[m][n] = (f32x4){0.f, 0.f, 0.f, 0.f};

    float4 rA[2];
    auto loadA = [&](int t) {
        const float* p = aBase + (size_t)arow * EH2 + t * 32 + ak8 * 8;
        rA[0] = ((const float4*)p)[0];
        rA[1] = ((const float4*)p)[1];
    };
    auto writeA = [&](int buf) {
        s16x8 hi = cvt8(rA[0], rA[1]);
        *(s16x8*)&sA[buf][swzA(arow, ak8)] = hi;
    };
    auto stageB = [&](int t, int buf) {
        const u16* tb = tBase + ((size_t)t << 14);
#pragma unroll
        for (int q = 0; q < 4; ++q) {
            int o = (wid * 4 + q) * 512;   // u16 units, 1 KB per inst
            __builtin_amdgcn_global_load_lds(
                (const __attribute__((address_space(1))) u32*)(tb + o + lane * 8),
                (__attribute__((address_space(3))) u32*)&sB[buf][o],
                16, 0, 0);
        }
    };

    auto compute = [&](int buf) {
        s16x8 bH[4], bL[4];
#pragma unroll
        for (int n = 0; n < 4; ++n) {
            int col = wn + n * 16 + lr;
            bH[n] = *(const s16x8*)&sB[buf][swzB(col, lg)];
            bL[n] = *(const s16x8*)&sB[buf][swzB(col, lg + 4)];
        }
        __builtin_amdgcn_s_setprio(1);
#pragma unroll
        for (int m = 0; m < 4; ++m) {
            int row = wm + m * 16 + lr;
            s16x8 aH = *(const s16x8*)&sA[buf][swzA(row, lg)];
#pragma unroll
            for (int n = 0; n < 4; ++n) {
                acc[m][n] = __builtin_amdgcn_mfma_f32_16x16x32_bf16(aH, bH[n], acc[m][n], 0, 0, 0);
                acc[m][n] = __builtin_amdgcn_mfma_f32_16x16x32_bf16(aH, bL[n], acc[m][n], 0, 0, 0);
            }
        }
        __builtin_amdgcn_s_setprio(0);
    };

    // ---- prologue: stage tile 0 into buf 0, prefetch A(1) regs
    loadA(0);
    stageB(0, 0);
    writeA(0);                 // auto-waits A(0); B(0) DMAs stay in flight
    loadA(1);
    asm volatile("s_waitcnt vmcnt(2) lgkmcnt(0)" ::: "memory");
    __builtin_amdgcn_s_barrier();

#pragma unroll 1
    for (int t = 0; t < 32; ++t) {
        const int cur = t & 1;
        __builtin_amdgcn_sched_barrier(0);
        if (t < 31) {
            stageB(t + 1, cur ^ 1);
            writeA(cur ^ 1);
            if (t < 30) loadA(t + 2);
        }
        compute(cur);
        if (t < 30) {
            asm volatile("s_waitcnt vmcnt(2) lgkmcnt(0)" ::: "memory");
        } else {
            asm volatile("s_waitcnt vmcnt(0) lgkmcnt(0)" ::: "memory");
        }
        __builtin_amdgcn_s_barrier();
    }

    // ---- epilogue: partial scores over this block's 256 cols, block-local
    float* sred = (float*)&sA[0][0];           // [4][128], aliased on dead sA[0]
    int* sflag = (int*)&sA[1][0];              // flag aliased on dead sA[1]
    float hp[4], vv[4];
#pragma unroll
    for (int n = 0; n < 4; ++n) {
        int c = d0 + wn + n * 16 + lr;
        hp[n] = hproj[b * DH + c];
        vv[n] = v[c];
    }
#pragma unroll
    for (int m = 0; m < 4; ++m)
#pragma unroll
        for (int r = 0; r < 4; ++r) {
            float p = 0.f;
#pragma unroll
            for (int n = 0; n < 4; ++n)
                p += fast_tanh(acc[m][n][r] + hp[n]) * vv[n];
            p += __shfl_xor(p, 1, 64);
            p += __shfl_xor(p, 2, 64);
            p += __shfl_xor(p, 4, 64);
            p += __shfl_xor(p, 8, 64);
            if (lr == 0)
                sred[(wid & 3) * 128 + wm + m * 16 + lg * 4 + r] = p;
        }
    __syncthreads();
    if (tid < 128) {
        float s = sred[0 * 128 + tid] + sred[1 * 128 + tid]
                + sred[2 * 128 + tid] + sred[3 * 128 + tid];
        scoresP[(size_t)nblk * BB * SS + b * SS + srow + tid] = s;
    }

    // ---- fused softmax: last of the 16 blocks for batch-row b does it
    __threadfence();                            // release scoresP writes
    if (tid == 0) sflag[0] = atomicAdd(&cnt[b], 1);
    __syncthreads();
    if (sflag[0] != 15) return;
    __threadfence();                            // acquire all 16 blocks' writes

    // 512 threads, 2 s-elements each
    float x0, x1;
    {
        int s0 = tid, s1 = tid + 512;
        float a0 = scoresP[b * SS + s0] + scoresP[BB * SS + b * SS + s0];
        float a1 = scoresP[b * SS + s1] + scoresP[BB * SS + b * SS + s1];
        if (mask[b * SS + s0] == 0) a0 = NEGV;
        if (mask[b * SS + s1] == 0) a1 = NEGV;
        x0 = a0; x1 = a1;
    }
    __syncthreads();                            // sred reuse: all reads done
    float* red = sred;
    float mx = fmaxf(x0, x1);
#pragma unroll
    for (int off = 32; off > 0; off >>= 1)
        mx = fmaxf(mx, __shfl_xor(mx, off, 64));
    if (lane == 0) red[wid] = mx;
    __syncthreads();
    mx = red[0];
#pragma unroll
    for (int w = 1; w < 8; ++w) mx = fmaxf(mx, red[w]);

    x0 = expf(x0 - mx);
    x1 = expf(x1 - mx);
    float sum = x0 + x1;
#pragma unroll
    for (int off = 32; off > 0; off >>= 1)
        sum += __shfl_xor(sum, off, 64);
    __syncthreads();
    if (lane == 0) red[8 + wid] = sum;
    __syncthreads();
    sum = red[8];
#pragma unroll
    for (int w = 1; w < 8; ++w) sum += red[8 + w];
    float inv = 1.0f / sum;
    out[b * SS + tid] = x0 * inv;
    out[b * SS + tid + 512] = x1 * inv;
}

extern "C" void kernel_launch(void* const* d_in, const int* in_sizes, int n_in,
                              void* d_out, int out_size, void* d_ws, size_t ws_size,
                              hipStream_t stream) {
    const float* hidden = (const float*)d_in[0];
    const float* enc    = (const float*)d_in[1];
    const int*   mask   = (const int*)d_in[2];
    const float* W      = (const float*)d_in[3];
    const float* bias   = (const float*)d_in[4];
    const float* v      = (const float*)d_in[5];
    float* out = (float*)d_out;

    float* hproj = (float*)d_ws;                          // 64 KB
    float* scoresP = (float*)((char*)d_ws + 64 * 1024);   // 2 planes x 128 KB
    int* cnt = (int*)((char*)d_ws + 320 * 1024);          // 32 ints
    u16* bimg = (u16*)((char*)d_ws + 324 * 1024);         // 2 MB swizzled tiles

    hipMemsetAsync(cnt, 0, BB * sizeof(int), stream);

    // fused prep: blocks 0..255 = bsplit, 256..4351 = hproj
    prep_kernel<<<256 + 4096, 256, 0, stream>>>(W, hidden, bias, bimg, hproj);
    energy_mfma_kernel<<<512, 512, 0, stream>>>(enc, bimg, hproj, v, mask,
                                                scoresP, cnt, out);
}

// Round 20
// 78.916 us; speedup vs baseline: 2.1857x; 1.7717x over previous
//
#include <hip/hip_runtime.h>
#include <hip/hip_bf16.h>
#include <math.h>

#define BB 32
#define SS 1024
#define DH 512      // DEC_HID
#define EH2 1024    // 2*ENC_HID
#define WROW 1536   // in_dim
#define NEGV -1.0e10f

typedef __attribute__((ext_vector_type(8))) short s16x8;
typedef __attribute__((ext_vector_type(4))) float f32x4;
typedef unsigned short u16;
typedef unsigned int u32;

// B LDS row = 128 B: [hi k0..31 | lo k0..31], 8 slots of 16 B, XOR-swizzled.
__device__ __forceinline__ int swzB(int row, int slot) {
    return row * 64 + ((slot ^ (row & 7)) << 3);
}
// A LDS row = 64 B (hi only): 4 slots of 16 B; 2-way-free swizzle.
__device__ __forceinline__ int swzA(int row, int slot) {
    return row * 32 + ((slot ^ ((row >> 1) & 3)) << 3);
}

__device__ __forceinline__ void split8(const float4& v0, const float4& v1,
                                       s16x8& hi, s16x8& lo) {
    float xs[8] = {v0.x, v0.y, v0.z, v0.w, v1.x, v1.y, v1.z, v1.w};
    union { u16 u[8]; s16x8 v; } H, L;
#pragma unroll
    for (int j = 0; j < 8; ++j) {
        u32 u = __builtin_bit_cast(u32, xs[j]);
        u32 hb = u & 0xFFFF0000u;
        float rem = xs[j] - __builtin_bit_cast(float, hb);
        H.u[j] = (u16)(u >> 16);
        L.u[j] = __builtin_bit_cast(u16, __float2bfloat16(rem));
    }
    hi = H.v;
    lo = L.v;
}

__device__ __forceinline__ s16x8 cvt8(const float4& v0, const float4& v1) {
    float xs[8] = {v0.x, v0.y, v0.z, v0.w, v1.x, v1.y, v1.z, v1.w};
    union { u16 u[8]; s16x8 v; } H;
#pragma unroll
    for (int j = 0; j < 8; ++j)
        H.u[j] = __builtin_bit_cast(u16, __float2bfloat16(xs[j]));   // RNE
    return H.v;
}

__device__ __forceinline__ float fast_tanh(float x) {
    float a = fabsf(x);
    float e = __expf(2.0f * a);
    float r = 1.0f - 2.0f / (e + 1.0f);   // e->inf gives r=1, no NaN
    return copysignf(r, x);
}

// ---------------- Prep kernel: fused bsplit (blocks 0..255) + hproj (256..4351)
__global__ void prep_kernel(const float* __restrict__ W,
                            const float* __restrict__ hidden,
                            const float* __restrict__ bias,
                            u16* __restrict__ img,
                            float* __restrict__ hproj) {
    if (blockIdx.x < 256) {
        int idx = blockIdx.x * 256 + threadIdx.x;   // 512 cols * 128 k-octets
        int c = idx >> 7;         // 0..511 (We row = output col d)
        int ko = idx & 127;       // k-octet 0..127
        int k = ko * 8;
        const float* src = W + (size_t)c * WROW + DH + k;
        float4 v0 = *(const float4*)src;
        float4 v1 = *(const float4*)(src + 4);
        s16x8 hi, lo;
        split8(v0, v1, hi, lo);
        int nb = c >> 8;          // n-block (256 cols each)
        int cp = c & 255;         // col within tile
        int kt = ko >> 2;         // K-step
        int sl = ko & 3;          // hi slot
        u16* tb = img + ((size_t)(nb * 32 + kt) << 14);   // 16384 u16 per tile
        *(s16x8*)(tb + swzB(cp, sl)) = hi;
        *(s16x8*)(tb + swzB(cp, sl + 4)) = lo;
    } else {
        int wave = (int)(((blockIdx.x - 256) * blockDim.x + threadIdx.x) >> 6);
        int lane = threadIdx.x & 63;
        if (wave >= BB * DH) return;
        int b = wave >> 9;
        int d = wave & 511;
        const float* hrow = hidden + b * DH;
        const float* wrow = W + (size_t)d * WROW;
        float sum = 0.f;
#pragma unroll
        for (int u = 0; u < 8; ++u) {
            int k = lane + 64 * u;
            sum = fmaf(hrow[k], wrow[k], sum);
        }
#pragma unroll
        for (int off = 32; off > 0; off >>= 1)
            sum += __shfl_xor(sum, off, 64);
        if (lane == 0) hproj[wave] = sum + bias[d];
    }
}

// ---------------- Kernel B: 128s x 256d block, 8 waves (2x4), wave-tile 64x64,
// 2-product bf16 split (A hi-only), FULL double-buffer, ONE barrier per K-step.
// LDS 80 KB -> 2 blocks/CU. grid: 512 blocks (256 m x 2 nb, XCD-chunked).
__global__ __launch_bounds__(512, 4)
void energy_mfma_kernel(const float* __restrict__ enc,
                        const u16* __restrict__ bimg,
                        const float* __restrict__ hproj,
                        const float* __restrict__ v,
                        float* __restrict__ scoresP) {
    __shared__ u16 sA[2][128 * 32];     // 8 KB each (hi only)
    __shared__ u16 sB[2][256 * 64];     // 32 KB each

    const int tid = threadIdx.x;
    const int lane = tid & 63;
    const int wid = tid >> 6;         // 0..7
    const int lr = lane & 15;
    const int lg = lane >> 4;         // 0..3

    // XCD-chunked decode (bijective: 512 = 8*64)
    const int flat = (blockIdx.x & 7) * 64 + (blockIdx.x >> 3);
    const int nblk = flat & 1;
    const int mblk = flat >> 1;       // 0..255
    const int b = mblk >> 3;
    const int srow = (mblk & 7) * 128;
    const int d0 = nblk * 256;

    const int wm = (wid >> 2) * 64;   // wave row offset (2 M-groups)
    const int wn = (wid & 3) * 64;    // wave col offset (4 N-waves)

    const float* aBase = enc + ((size_t)(b * SS + srow)) * EH2;
    const u16* tBase = bimg + (((size_t)nblk * 32) << 14);

    const int arow = tid >> 2;        // 0..127
    const int ak8 = tid & 3;          // k-octet 0..3

    f32x4 acc[4][4];
#pragma unroll
    for (int m = 0; m < 4; ++m)
#pragma unroll
        for (int n = 0; n < 4; ++n) acc[m][n] = (f32x4){0.f, 0.f, 0.f, 0.f};

    float4 rA[2];
    auto loadA = [&](int t) {
        const float* p = aBase + (size_t)arow * EH2 + t * 32 + ak8 * 8;
        rA[0] = ((const float4*)p)[0];
        rA[1] = ((const float4*)p)[1];
    };
    auto writeA = [&](int buf) {
        s16x8 hi = cvt8(rA[0], rA[1]);
        *(s16x8*)&sA[buf][swzA(arow, ak8)] = hi;
    };
    auto stageB = [&](int t, int buf) {
        const u16* tb = tBase + ((size_t)t << 14);
#pragma unroll
        for (int q = 0; q < 4; ++q) {
            int o = (wid * 4 + q) * 512;   // u16 units, 1 KB per inst
            __builtin_amdgcn_global_load_lds(
                (const __attribute__((address_space(1))) u32*)(tb + o + lane * 8),
                (__attribute__((address_space(3))) u32*)&sB[buf][o],
                16, 0, 0);
        }
    };

    auto compute = [&](int buf) {
        s16x8 bH[4], bL[4];
#pragma unroll
        for (int n = 0; n < 4; ++n) {
            int col = wn + n * 16 + lr;
            bH[n] = *(const s16x8*)&sB[buf][swzB(col, lg)];
            bL[n] = *(const s16x8*)&sB[buf][swzB(col, lg + 4)];
        }
        __builtin_amdgcn_s_setprio(1);
#pragma unroll
        for (int m = 0; m < 4; ++m) {
            int row = wm + m * 16 + lr;
            s16x8 aH = *(const s16x8*)&sA[buf][swzA(row, lg)];
#pragma unroll
            for (int n = 0; n < 4; ++n) {
                acc[m][n] = __builtin_amdgcn_mfma_f32_16x16x32_bf16(aH, bH[n], acc[m][n], 0, 0, 0);
                acc[m][n] = __builtin_amdgcn_mfma_f32_16x16x32_bf16(aH, bL[n], acc[m][n], 0, 0, 0);
            }
        }
        __builtin_amdgcn_s_setprio(0);
    };

    // ---- prologue: stage tile 0 into buf 0, prefetch A(1) regs
    loadA(0);
    stageB(0, 0);
    writeA(0);                 // auto-waits A(0); B(0) DMAs stay in flight
    loadA(1);
    asm volatile("s_waitcnt vmcnt(2) lgkmcnt(0)" ::: "memory");
    __builtin_amdgcn_s_barrier();

#pragma unroll 1
    for (int t = 0; t < 32; ++t) {
        const int cur = t & 1;
        __builtin_amdgcn_sched_barrier(0);     // nothing hoists above the barrier
        if (t < 31) {
            stageB(t + 1, cur ^ 1);            // 4 DMAs into other buffer
            writeA(cur ^ 1);                   // waits A(t+1) regs; ds_writes other buffer
            if (t < 30) loadA(t + 2);          // 2 vmem, stay in flight across barrier
        }
        compute(cur);                          // 12 ds_read + 32 MFMA, same region
        if (t < 30) {
            asm volatile("s_waitcnt vmcnt(2) lgkmcnt(0)" ::: "memory"); // drain B(t+1); keep A(t+2)
        } else {
            asm volatile("s_waitcnt vmcnt(0) lgkmcnt(0)" ::: "memory");
        }
        __builtin_amdgcn_s_barrier();          // single barrier per step
    }

    // ---- epilogue: partial scores over this block's 256 cols, block-local
    float* sred = (float*)&sA[0][0];           // [4][128], aliased on dead sA
    float hp[4], vv[4];
#pragma unroll
    for (int n = 0; n < 4; ++n) {
        int c = d0 + wn + n * 16 + lr;
        hp[n] = hproj[b * DH + c];
        vv[n] = v[c];
    }
#pragma unroll
    for (int m = 0; m < 4; ++m)
#pragma unroll
        for (int r = 0; r < 4; ++r) {
            float p = 0.f;
#pragma unroll
            for (int n = 0; n < 4; ++n)
                p += fast_tanh(acc[m][n][r] + hp[n]) * vv[n];
            p += __shfl_xor(p, 1, 64);
            p += __shfl_xor(p, 2, 64);
            p += __shfl_xor(p, 4, 64);
            p += __shfl_xor(p, 8, 64);
            if (lr == 0)
                sred[(wid & 3) * 128 + wm + m * 16 + lg * 4 + r] = p;
        }
    __syncthreads();
    if (tid < 128) {
        float s = sred[0 * 128 + tid] + sred[1 * 128 + tid]
                + sred[2 * 128 + tid] + sred[3 * 128 + tid];
        scoresP[(size_t)nblk * BB * SS + b * SS + srow + tid] = s;
    }
}

// ---------------- Kernel C: masked softmax over S (sums the 2 nblk planes)
__global__ void softmax_kernel(const float* __restrict__ scoresP,
                               const int* __restrict__ mask,
                               float* __restrict__ out) {
    __shared__ float red[8];
    int b = blockIdx.x;
    int tid = threadIdx.x;
    int lane = tid & 63;
    int wid = tid >> 6;

    float x[4];
    float mx = -INFINITY;
#pragma unroll
    for (int u = 0; u < 4; ++u) {
        int s = tid + 256 * u;
        float sc = scoresP[b * SS + s] + scoresP[BB * SS + b * SS + s];
        if (mask[b * SS + s] == 0) sc = NEGV;
        x[u] = sc;
        mx = fmaxf(mx, sc);
    }
#pragma unroll
    for (int off = 32; off > 0; off >>= 1)
        mx = fmaxf(mx, __shfl_xor(mx, off, 64));
    if (lane == 0) red[wid] = mx;
    __syncthreads();
    mx = fmaxf(fmaxf(red[0], red[1]), fmaxf(red[2], red[3]));

    float sum = 0.f;
#pragma unroll
    for (int u = 0; u < 4; ++u) {
        x[u] = expf(x[u] - mx);
        sum += x[u];
    }
#pragma unroll
    for (int off = 32; off > 0; off >>= 1)
        sum += __shfl_xor(sum, off, 64);
    __syncthreads();
    if (lane == 0) red[4 + wid] = sum;
    __syncthreads();
    sum = red[4] + red[5] + red[6] + red[7];
    float inv = 1.0f / sum;
#pragma unroll
    for (int u = 0; u < 4; ++u)
        out[b * SS + tid + 256 * u] = x[u] * inv;
}

extern "C" void kernel_launch(void* const* d_in, const int* in_sizes, int n_in,
                              void* d_out, int out_size, void* d_ws, size_t ws_size,
                              hipStream_t stream) {
    const float* hidden = (const float*)d_in[0];
    const float* enc    = (const float*)d_in[1];
    const int*   mask   = (const int*)d_in[2];
    const float* W      = (const float*)d_in[3];
    const float* bias   = (const float*)d_in[4];
    const float* v      = (const float*)d_in[5];
    float* out = (float*)d_out;

    float* hproj = (float*)d_ws;                          // 64 KB
    float* scoresP = (float*)((char*)d_ws + 64 * 1024);   // 2 planes x 128 KB
    u16* bimg = (u16*)((char*)d_ws + 320 * 1024);         // 2 MB swizzled tiles

    // fused prep: blocks 0..255 = bsplit, 256..4351 = hproj
    prep_kernel<<<256 + 4096, 256, 0, stream>>>(W, hidden, bias, bimg, hproj);
    energy_mfma_kernel<<<512, 512, 0, stream>>>(enc, bimg, hproj, v, scoresP);
    softmax_kernel<<<BB, 256, 0, stream>>>(scoresP, mask, out);
}